// Round 10
// baseline (367.801 us; speedup 1.0000x reference)
//
#include <hip/hip_runtime.h>

#define BATCH 16
#define NQ    2048
#define NKV   2048
#define DH    64
// (1/sqrt(64)) * log2(e): softmax in exp2 domain, scale folded into Q cast.
#define SC    0.18033688011112042f
#define TILE_B 8192     // per 32-key tile: 4KB K frags + 4KB V frags (per-lane order)
#define EP     4        // epilogue cost (tile-units) for work balancing
#define GBLK   1024
// ws layout: [0,8MB) tile images | partial slots 1024 qids x 16 x 8448B | counters
#define PART_OFF 8388608u
#define CNT_OFF  146800640u   // 8388608 + 1024*16*8448

typedef __attribute__((ext_vector_type(8))) short  bf16x8;
typedef __attribute__((ext_vector_type(4))) unsigned u32x4;
typedef __attribute__((ext_vector_type(16))) float f32x16;

__device__ __forceinline__ unsigned f2bf(float f) {  // RNE, finite inputs
  unsigned u = __builtin_bit_cast(unsigned, f);
  u += 0x7FFFu + ((u >> 16) & 1u);
  return u >> 16;
}

// ---- pre-pass: K/V fp32 -> bf16 fragment images in WS + zero fixup counters ----
// K chunk c (A-op of S^T, m=key): lane l holds K[key=l&31][d=c*16+(l>>5)*8+j] at tile+c*1024+l*16.
// V chunk g=dh*2+c2 (A-op of O^T): lane l holds
//   V[key=c2*16+(j&3)+8*(j>>2)+4*(l>>5)][d=dh*32+(l&31)] at tile+4096+g*1024+l*16.
__global__ __launch_bounds__(256) void convert_kernel(
    const float* __restrict__ K, const float* __restrict__ V,
    const int* __restrict__ lens, unsigned char* __restrict__ WS) {
  const int bt = blockIdx.x;  // b*64 + t; also doubles as qid for counter zeroing
  if (threadIdx.x == 0) ((int*)(WS + CNT_OFF))[bt] = 0;
  const int b = bt >> 6, t = bt & 63;
  const int L = lens[b];
  const int Leff = (L == 0) ? NKV : L;
  if (t * 32 >= Leff) return;  // dead tile: never read by sdpa

  unsigned char* tile = WS + (size_t)bt * TILE_B;
  const size_t   srow = ((size_t)b * NKV + (size_t)t * 32) * DH;
  const int tid = threadIdx.x;
  const int l = tid & 63, g = tid >> 6;
  const int l31 = l & 31, hi = l >> 5;
  {  // K chunk g
    const float4* p = (const float4*)(K + srow + (size_t)l31 * DH + g * 16 + hi * 8);
    float4 a = p[0], c4 = p[1];
    bf16x8 w;
    w[0] = (short)f2bf(a.x);  w[1] = (short)f2bf(a.y);
    w[2] = (short)f2bf(a.z);  w[3] = (short)f2bf(a.w);
    w[4] = (short)f2bf(c4.x); w[5] = (short)f2bf(c4.y);
    w[6] = (short)f2bf(c4.z); w[7] = (short)f2bf(c4.w);
    *(bf16x8*)(tile + g * 1024 + l * 16) = w;
  }
  {  // V chunk g: c2 = g&1 (key half), dh = g>>1 (d half)
    const int c2 = g & 1, dh = g >> 1;
    const float* vp = V + srow + (size_t)(c2 * 16 + 4 * hi) * DH + dh * 32 + l31;
    bf16x8 w;
#pragma unroll
    for (int j = 0; j < 8; ++j)
      w[j] = (short)f2bf(vp[(size_t)((j & 3) + 8 * (j >> 2)) * DH]);
    *(bf16x8*)(tile + 4096 + g * 1024 + l * 16) = w;
  }
}

// ---- main: stream-K. 1024 blocks each take an EQUAL contiguous range of the
// global tile-unit list (item = q-tile, cost nT(b)+EP). Boundary q-tiles merge
// via split-K fixup (dump + device fence + counter; last block stores).
__global__ __launch_bounds__(256, 3) void sdpa_kernel(
    const float* __restrict__ Q, unsigned char* __restrict__ WS,
    const int* __restrict__ lens, float* __restrict__ O) {
  __shared__ float smem[3 * 2112];
  __shared__ int   sflag;

  const int tid  = threadIdx.x;
  const int lane = tid & 63;
  const int wave = tid >> 6;
  const int l31  = lane & 31, hi = lane >> 5;
  const int idx  = blockIdx.x;

  // total balanced work W = sum_b 64*(nT(b)+EP)  (uniform across blocks)
  long long W = 0;
#pragma unroll
  for (int bb = 0; bb < 16; ++bb) {
    const int L = lens[bb];
    const int Leff = (L == 0) ? NKV : L;
    W += 64ll * (((Leff + 31) >> 5) + EP);
  }
  const long long s = (long long)idx * W / GBLK;
  const long long e = (long long)(idx + 1) * W / GBLK;

  // locate starting batch/item (sequential scan, no arrays -> low VGPR)
  long long cum = 0;
  int b = 0, nT = 0, cb = 0;
  for (;;) {
    const int L = lens[b];
    const int Leff = (L == 0) ? NKV : L;
    nT = (Leff + 31) >> 5;
    cb = nT + EP;
    const long long nb = 64ll * cb;
    if (cum + nb > s) break;
    cum += nb;
    ++b;
  }
  int       item   = (int)((s - cum) / cb);
  long long istart = cum + (long long)item * cb;
  int       u0     = (int)(s - istart);

  float* PART = (float*)(WS + PART_OFF);
  int*   CNT  = (int*)(WS + CNT_OFF);

  while (istart < e) {
    const int  L    = lens[b];
    const bool zlen = (L == 0);
    const int  t0   = (u0 < nT) ? u0 : nT;
    const long long rem = e - istart;
    const int  t1   = (rem < (long long)nT) ? (int)rem : nT;

    if (t0 < t1) {  // block-uniform predicate -> barriers safe
      const int qo    = item;
      const int tmask = (!zlen && (L & 31)) ? nT - 1 : -1;
      const int len   = t1 - t0;
      const int wt0   = t0 + ((len * wave) >> 2);
      const int cnt   = t0 + ((len * (wave + 1)) >> 2) - wt0;

      // Q frags (B-op of S^T: n=l31=q, k-slot hi*8+j -> d=c*16+hi*8+j), pre-scaled
      bf16x8 Qf[4];
      {
        const float  sc = zlen ? 0.f : SC;  // zlen: S=0 -> p=1 (uniform softmax)
        const float* qp = Q + ((size_t)b * NQ + qo * 32 + l31) * DH + hi * 8;
#pragma unroll
        for (int c = 0; c < 4; ++c) {
          const float4* p = (const float4*)(qp + c * 16);
          float4 a = p[0], d4 = p[1];
          bf16x8 w;
          w[0] = (short)f2bf(a.x * sc);  w[1] = (short)f2bf(a.y * sc);
          w[2] = (short)f2bf(a.z * sc);  w[3] = (short)f2bf(a.w * sc);
          w[4] = (short)f2bf(d4.x * sc); w[5] = (short)f2bf(d4.y * sc);
          w[6] = (short)f2bf(d4.z * sc); w[7] = (short)f2bf(d4.w * sc);
          Qf[c] = w;
        }
      }

      f32x16 oc0, oc1;
      float  l_ = 0.f;
#pragma unroll
      for (int r = 0; r < 16; ++r) { oc0[r] = 0.f; oc1[r] = 0.f; }

      const unsigned char* gp = WS + (size_t)(b * 64 + wt0) * TILE_B + (size_t)lane * 16;
      bf16x8 cur[8];
      if (cnt > 0) {
#pragma unroll
        for (int i = 0; i < 8; ++i) cur[i] = *(const bf16x8*)(gp + i * 1024);
      }

#pragma unroll 2
      for (int it = 0; it < cnt; ++it) {
        const int t = wt0 + it;
        const unsigned char* gn = (it + 1 < cnt) ? (gp + TILE_B) : gp;
        bf16x8 nxt[8];
#pragma unroll
        for (int i = 0; i < 8; ++i) nxt[i] = *(const bf16x8*)(gn + i * 1024);
        gp += TILE_B;

        // S^T = K Q^T (32k x 32q): lane col=q, reg r -> key (r&3)+8*(r>>2)+4*hi
        f32x16 acc;
#pragma unroll
        for (int r = 0; r < 16; ++r) acc[r] = 0.f;
#pragma unroll
        for (int c = 0; c < 4; ++c)
          acc = __builtin_amdgcn_mfma_f32_32x32x16_bf16(cur[c], Qf[c], acc, 0, 0, 0);

        if (t == tmask) {
#pragma unroll
          for (int r = 0; r < 16; ++r) {
            const int key = t * 32 + (r & 3) + 8 * (r >> 2) + 4 * hi;
            if (key >= L) acc[r] = -1e30f;
          }
        }

        // fixed-max softmax: p=exp2(z); l from full p; P^T packed via v_perm
        unsigned pi[16];
        float ls = 0.f;
#pragma unroll
        for (int r = 0; r < 16; ++r) {
          float p = __builtin_amdgcn_exp2f(acc[r]);
          ls += p;
          pi[r] = __builtin_bit_cast(unsigned, p) + 0x8000u;
        }
        l_ += ls;

        u32x4 t0v, t1v;
#pragma unroll
        for (int w = 0; w < 4; ++w) {
          t0v[w] = __builtin_amdgcn_perm(pi[2 * w + 1], pi[2 * w], 0x07060302u);
          t1v[w] = __builtin_amdgcn_perm(pi[8 + 2 * w + 1], pi[8 + 2 * w], 0x07060302u);
        }
        bf16x8 Pf0 = __builtin_bit_cast(bf16x8, t0v);
        bf16x8 Pf1 = __builtin_bit_cast(bf16x8, t1v);

        oc0 = __builtin_amdgcn_mfma_f32_32x32x16_bf16(cur[4], Pf0, oc0, 0, 0, 0);
        oc0 = __builtin_amdgcn_mfma_f32_32x32x16_bf16(cur[5], Pf1, oc0, 0, 0, 0);
        oc1 = __builtin_amdgcn_mfma_f32_32x32x16_bf16(cur[6], Pf0, oc1, 0, 0, 0);
        oc1 = __builtin_amdgcn_mfma_f32_32x32x16_bf16(cur[7], Pf1, oc1, 0, 0, 0);

#pragma unroll
        for (int i = 0; i < 8; ++i) cur[i] = nxt[i];
      }

      // ---- internal 4-wave merge -> block TOTAL in smem[0..2112) layout [33][64] ----
      __syncthreads();  // smem reuse guard across items
      if (wave >= 1) {
        float* Mb = smem + (wave - 1) * 2112 + lane;
#pragma unroll
        for (int r = 0; r < 16; ++r) { Mb[r * 64] = oc0[r]; Mb[(16 + r) * 64] = oc1[r]; }
        Mb[32 * 64] = l_;
      }
      __syncthreads();
      if (wave == 0) {
#pragma unroll
        for (int w = 0; w < 3; ++w) {
          const float* Mb = smem + w * 2112 + lane;
#pragma unroll
          for (int r = 0; r < 16; ++r) { oc0[r] += Mb[r * 64]; oc1[r] += Mb[(16 + r) * 64]; }
          l_ += Mb[32 * 64];
        }
#pragma unroll
        for (int r = 0; r < 16; ++r) {
          smem[r * 64 + lane]        = oc0[r];
          smem[(16 + r) * 64 + lane] = oc1[r];
        }
        smem[32 * 64 + lane] = l_;
      }
      __syncthreads();

      // ---- split-K fixup if this q-tile spans multiple blocks ----
      const int f0    = (int)(((istart + 1) * GBLK - 1) / W);
      const int f1    = (int)(((istart + nT) * GBLK - 1) / W);
      const int npart = f1 - f0 + 1;
      bool doStore = true;
      const int qid = b * 64 + qo;
      if (npart > 1) {
        const int j = idx - f0;  // distinct per contributing block, <16 (bounded)
        float* dst = PART + (size_t)(qid * 16 + j) * 2112;
#pragma unroll
        for (int k = 0; k < 9; ++k) {
          const int ii = k * 256 + tid;
          if (ii < 2112) dst[ii] = smem[ii];
        }
        __threadfence();
        __syncthreads();
        if (tid == 0) sflag = atomicAdd(&CNT[qid], 1);
        __syncthreads();
        if (sflag != npart - 1) {
          doStore = false;  // another block will finish this q-tile
        } else {
          __threadfence();
          for (int jj = 0; jj < npart; ++jj) {
            if (jj == idx - f0) continue;
            const float* src = PART + (size_t)(qid * 16 + jj) * 2112;
#pragma unroll
            for (int k = 0; k < 9; ++k) {
              const int ii = k * 256 + tid;
              if (ii < 2112) smem[ii] += src[ii];
            }
          }
          __syncthreads();
        }
      }

      if (doStore) {
        // all-thread normalize + store: thread -> (q = tid>>3, 8 consecutive d)
        const int   q   = tid >> 3, db = (tid & 7) * 8;
        const float lq  = smem[32 * 64 + q] + smem[32 * 64 + 32 + q];
        const float inv = 1.0f / lq;
        float out[8];
#pragma unroll
        for (int dd = 0; dd < 8; ++dd) {
          const int d = db + dd, dh = d >> 5, d5 = d & 31;
          const int h2 = (d5 >> 2) & 1, r = (d5 & 3) | ((d5 >> 3) << 2);
          out[dd] = smem[(dh * 16 + r) * 64 + h2 * 32 + q] * inv;
        }
        float* Ob = O + ((size_t)b * NQ + qo * 32 + q) * DH + db;
        *(float4*)Ob       = (float4){out[0], out[1], out[2], out[3]};
        *(float4*)(Ob + 4) = (float4){out[4], out[5], out[6], out[7]};
      }
    }

    // advance to next item
    istart += cb;
    ++item;
    u0 = 0;
    if (item >= 64) {
      ++b;
      item = 0;
      if (b < BATCH) {
        const int L2 = lens[b];
        const int Le = (L2 == 0) ? NKV : L2;
        nT = (Le + 31) >> 5;
        cb = nT + EP;
      }
    }
  }
}

extern "C" void kernel_launch(void* const* d_in, const int* in_sizes, int n_in,
                              void* d_out, int out_size, void* d_ws, size_t ws_size,
                              hipStream_t stream) {
  const float* Q    = (const float*)d_in[0];
  const float* K    = (const float*)d_in[1];
  const float* V    = (const float*)d_in[2];
  const int*   lens = (const int*)d_in[3];
  float*       Out  = (float*)d_out;
  unsigned char* WS = (unsigned char*)d_ws;  // uses ~147 MB (tiles + partials + counters)

  hipLaunchKernelGGL(convert_kernel, dim3(BATCH * 64), dim3(256), 0, stream, K, V, lens, WS);
  hipLaunchKernelGGL(sdpa_kernel, dim3(GBLK), dim3(256), 0, stream, Q, WS, lens, Out);
}